// Round 10
// baseline (56.715 us; speedup 1.0000x reference)
//
#include <hip/hip_runtime.h>
#include <stdint.h>

#define NB   16
#define CIN  32
#define COUT 32
#define HH   256
#define WW   256
#define HWSZ (HH * WW)
#define EPSV 1e-5f
#define NSLOT 6
#define TWD   264    // LDS row words: zero pads at index 3 and 260, data at 4..259

typedef int v4i  __attribute__((ext_vector_type(4)));
typedef int v16i __attribute__((ext_vector_type(16)));

// ---------------------------------------------------------------------------
// Kernel 1 (tiny, 1 block): weight pack -> MFMA A-fragments + BN/correction
// tables. wb = sign(sign(w)+0.01): -1 iff w<0, +1 otherwise.
//   afrag[t*64+lane] = 16 i8 (+-1): o = lane&31, ch = (lane>>5)*16 + e
//   c0f[cls*32+o] = beta - mean*inv + Wsum[cls][o]*inv
//   c0f[288+o]    = -2 * gamma/sqrt(var+eps)   (c1, appended)
// B-matrix bit = signbit(x) (1 iff x<0), pads/invalid taps = 0. Then
//   conv = Wsum_valid - 2*acc  ->  result = acc*c1 + c0.
// ---------------------------------------------------------------------------
__global__ __launch_bounds__(288) void pack_w_kernel(
    const float* __restrict__ wt, const float* __restrict__ gamma,
    const float* __restrict__ beta, const float* __restrict__ rmean,
    const float* __restrict__ rvar, uint4* __restrict__ afrag,
    float* __restrict__ c0f) {
    __shared__ uint32_t pws[COUT * 9];
    const int j = threadIdx.x;                 // 0..287
    if (j < COUT * 9) {
        const int o = j / 9, t = j % 9;
        uint32_t bits = 0;
#pragma unroll
        for (int c = 0; c < CIN; ++c)
            bits |= (wt[(o * CIN + c) * 9 + t] < 0.f) ? (1u << c) : 0u;  // 1 = -1
        pws[j] = bits;
    }
    __syncthreads();
    if (j < 64) {
        const int sh = (j & 32) >> 1;          // channel half 0/16
#pragma unroll
        for (int t = 0; t < 9; ++t) {
            const uint32_t chunk = pws[(j & 31) * 9 + t] >> sh;
            uint32_t w[4];
#pragma unroll
            for (int k = 0; k < 4; ++k) {
                const uint32_t y = (((chunk >> (4 * k)) & 0xFu) * 0x204081u) & 0x01010101u;
                w[k] = (y * 0xFEu) | 0x01010101u;   // bit? 0xFF(-1) : 0x01(+1)
            }
            afrag[t * 64 + j] = make_uint4(w[0], w[1], w[2], w[3]);
        }
    }
    {
        const int cls = j >> 5;                // 0..8
        const int o   = j & 31;
        const int rc = cls / 3, cc = cls % 3;
        int wsum = 0;
#pragma unroll
        for (int dh = 0; dh < 3; ++dh)
#pragma unroll
            for (int dw = 0; dw < 3; ++dw) {
                const bool bad = (rc == 0 && dh == 0) || (rc == 2 && dh == 2) ||
                                 (cc == 0 && dw == 0) || (cc == 2 && dw == 2);
                if (!bad) wsum += 32 - 2 * __popc(pws[o * 9 + dh * 3 + dw]);
            }
        const float inv = gamma[o] * rsqrtf(rvar[o] + EPSV);
        c0f[cls * 32 + o] = beta[o] - rmean[o] * inv + (float)wsum * inv;
        if (cls == 0) c0f[288 + o] = -2.0f * inv;
    }
}

// circular slot index, v in [0, 11]
__device__ __forceinline__ int slot6(int v) { return (v >= NSLOT) ? (v - NSLOT) : v; }

// ---------------------------------------------------------------------------
// Kernel 2: pipelined 8-row strip kernel (round-5 schedule, spill-fixed).
// Block = (n, 8 output rows), 512 threads, 512 blocks (1.25x pack redundancy:
// 10 staged rows / 8 output rows). 6-slot circular LDS buffer of bit-packed
// rows (bit c = signbit(x), pads = 0). Per pair-iteration j:
//   conv rows h0+2j, h0+2j+1 from slots (2j..2j+3)%6  (round-8 inner loop,
//   A-fragments read per-tap from LDS -> no af[9] registers),
//   land in-flight prefetch (rows 2j+4, 2j+5) -> LDS,
//   issue loads for rows 2j+6, 2j+7 (1 px/thread, 32 dword loads -> pf[32]),
//   one barrier per iteration.
// ---------------------------------------------------------------------------
__global__ __launch_bounds__(512, 2) void biconv_mfma(
    const uint32_t* __restrict__ x, const uint4* __restrict__ afrag,
    const float* __restrict__ c0f, float* __restrict__ out) {
    const uint32_t bid = blockIdx.x;                      // 0..511
    const uint32_t wg  = ((bid & 7u) << 6) | (bid >> 3);  // bijective XCD chunk
    const int n   = wg >> 5;                              // 0..15
    const int h0  = (wg & 31) << 3;                       // strip base row
    const int tid  = threadIdx.x;
    const int lane = tid & 63;
    const int wave = tid >> 6;

    __shared__ uint32_t tiles[NSLOT][TWD];
    __shared__ uint4    afsh[9 * 64];     // 9216 B
    __shared__ float    csh[320];         // c0[0..287], c1[288..319]

    // ---- stage A-fragments + BN tables, zero slot pads ----
    for (int i = tid; i < 576; i += 512) afsh[i] = afrag[i];
    if (tid < 320) csh[tid] = c0f[tid];
    if (tid < NSLOT * 2) tiles[tid >> 1][(tid & 1) ? 260 : 3] = 0u;

    const uint32_t* xn = x + (size_t)n * (CIN * HWSZ);
    const int mypx = tid & 255;

    // ---- prologue: pack rows k=0..3 (2 tasks/thread, 1 px each) ----
#pragma unroll
    for (int it = 0; it < 2; ++it) {
        const int k  = (tid >> 8) + it * 2;    // 0..3
        const int hr = h0 - 1 + k;             // only k=0,h0=0 is OOB (<0)
        uint32_t b = 0;
        if (hr >= 0) {
            const uint32_t* xp = xn + (size_t)hr * WW + mypx;
#pragma unroll
            for (int c = 0; c < CIN; ++c) b |= (xp[(size_t)c * HWSZ] >> 31) << c;
        }
        tiles[k][mypx + 4] = b;
    }
    // ---- issue prefetch for rows k=4,5 (hr <= 252, always in bounds) ----
    uint32_t pf[CIN];
    {
        const int hr = h0 + 3 + (tid >> 8);
        const uint32_t* xp = xn + (size_t)hr * WW + mypx;
#pragma unroll
        for (int c = 0; c < CIN; ++c) pf[c] = xp[(size_t)c * HWSZ];
    }
    __syncthreads();

    // ---- main loop: 4 row-pairs ----
    const int l31  = lane & 31;
    const int shv  = (lane & 32) >> 1;     // channel half for B expansion
    const int og   = (lane >> 5) << 2;     // C/D row offset 0/4
    const int rsel = wave >> 2;            // row within pair: 0/1
    const int pA   = ((wave & 3) << 6) + l31;   // tile A pixel
    const int pB   = pA + 32;                   // tile B pixel
    const int ccA  = (pA == 0) ? 0 : ((pA == WW - 1) ? 2 : 1);
    const int ccB  = (pB == WW - 1) ? 2 : 1;    // pB >= 32, never 0
    const float* c1 = &csh[288];

#pragma unroll
    for (int j = 0; j < 4; ++j) {
        const int h  = h0 + 2 * j + rsel;
        const int rc = (h == 0) ? 0 : ((h == HH - 1) ? 2 : 1);
        const int kbase = 2 * j + rsel;         // staged row for dh=0
        v16i acc0 = {0}, acc1 = {0};
#pragma unroll
        for (int dh = 0; dh < 3; ++dh) {
            const uint32_t* trow = tiles[slot6(kbase + dh)];
#pragma unroll
            for (int dw = 0; dw < 3; ++dw) {
                const v4i a = *reinterpret_cast<const v4i*>(&afsh[(dh * 3 + dw) * 64 + lane]);
                const uint32_t hA = trow[pA + 3 + dw] >> shv;
                const uint32_t hB = trow[pB + 3 + dw] >> shv;
                v4i b;
                b.x = (int)((( hA        & 0xFu) * 0x204081u) & 0x01010101u);
                b.y = (int)((((hA >> 4)  & 0xFu) * 0x204081u) & 0x01010101u);
                b.z = (int)((((hA >> 8)  & 0xFu) * 0x204081u) & 0x01010101u);
                b.w = (int)((((hA >> 12) & 0xFu) * 0x204081u) & 0x01010101u);
                acc0 = __builtin_amdgcn_mfma_i32_32x32x32_i8(a, b, acc0, 0, 0, 0);
                b.x = (int)((( hB        & 0xFu) * 0x204081u) & 0x01010101u);
                b.y = (int)((((hB >> 4)  & 0xFu) * 0x204081u) & 0x01010101u);
                b.z = (int)((((hB >> 8)  & 0xFu) * 0x204081u) & 0x01010101u);
                b.w = (int)((((hB >> 12) & 0xFu) * 0x204081u) & 0x01010101u);
                acc1 = __builtin_amdgcn_mfma_i32_32x32x32_i8(a, b, acc1, 0, 0, 0);
            }
        }
        // ---- epilogue: C/D row = (e&3)+8*(e>>2)+og, col = pixel ----
        const float* c0A = &csh[(rc * 3 + ccA) * 32];
        const float* c0B = &csh[(rc * 3 + ccB) * 32];
        float* outn = out + (size_t)n * (COUT * HWSZ) + (size_t)h * WW;
#pragma unroll
        for (int e = 0; e < 16; ++e) {
            const int o = (e & 3) + ((e >> 2) << 3) + og;
            const float vA = fmaf((float)acc0[e], c1[o], c0A[o]);
            const float vB = fmaf((float)acc1[e], c1[o], c0B[o]);
            __builtin_nontemporal_store(vA > 0.f ? vA : 0.f, outn + (size_t)o * HWSZ + pA);
            __builtin_nontemporal_store(vB > 0.f ? vB : 0.f, outn + (size_t)o * HWSZ + pB);
        }
        // ---- pipeline: land prefetched rows, issue next ----
        if (j < 3) {
            const int kw  = 2 * j + 4 + (tid >> 8);
            const int hrw = h0 - 1 + kw;        // OOB only kw=9 on last strip
            uint32_t b = 0;
            if (hrw < HH) {
#pragma unroll
                for (int c = 0; c < CIN; ++c) b |= (pf[c] >> 31) << c;
            }
            tiles[slot6(kw)][mypx + 4] = b;
            if (j < 2) {
                const int kn  = 2 * j + 6 + (tid >> 8);
                const int hrn = h0 - 1 + kn;
                if (hrn < HH) {
                    const uint32_t* xp = xn + (size_t)hrn * WW + mypx;
#pragma unroll
                    for (int c = 0; c < CIN; ++c) pf[c] = xp[(size_t)c * HWSZ];
                }
            }
            __syncthreads();
        }
    }
}

// ---------------------------------------------------------------------------
extern "C" void kernel_launch(void* const* d_in, const int* in_sizes, int n_in,
                              void* d_out, int out_size, void* d_ws, size_t ws_size,
                              hipStream_t stream) {
    const float* x     = (const float*)d_in[0];
    const float* wt    = (const float*)d_in[1];
    const float* gamma = (const float*)d_in[2];
    const float* beta  = (const float*)d_in[3];
    const float* rmean = (const float*)d_in[4];
    const float* rvar  = (const float*)d_in[5];
    float* out = (float*)d_out;

    uint4* afrag = (uint4*)d_ws;                           // 9*64*16 = 9216 B
    float* c0f   = (float*)((char*)d_ws + 9216);           // 288 + 32 floats

    pack_w_kernel<<<dim3(1), dim3(288), 0, stream>>>(wt, gamma, beta, rmean,
                                                     rvar, afrag, c0f);
    biconv_mfma<<<dim3(NB * HH / 8), dim3(512), 0, stream>>>(
        (const uint32_t*)x, afrag, c0f, out);
}

// Round 11
// 47.792 us; speedup vs baseline: 1.1867x; 1.1867x over previous
//
#include <hip/hip_runtime.h>
#include <stdint.h>

#define NB   16
#define CIN  32
#define COUT 32
#define HH   256
#define WW   256
#define HWSZ (HH * WW)
#define EPSV 1e-5f
#define TWD  264     // LDS row words: zero pads at index 3 and 260, data at 4..259

typedef int v4i  __attribute__((ext_vector_type(4)));
typedef int v16i __attribute__((ext_vector_type(16)));

// ---------------------------------------------------------------------------
// Single fused kernel: binarize + implicit-GEMM i8-MFMA conv + BN + ReLU,
// with per-block weight prep (no producer kernel, single launch).
//
// Math: wb = sign(sign(w)+0.01) = -1 iff w<0, +1 otherwise. B-matrix bit =
// signbit(x) (1 iff x<0), pads/invalid taps = 0, A holds wb as i8 +-1:
//   acc = sum_{x<0} wb  ->  conv = Wsum_valid - 2*acc
//   result = acc*c1 + c0,  c1 = -2*inv,  c0 = beta - mean*inv + Wsum*inv,
//   inv = gamma/sqrt(var+eps).   Boundary classes (9) fold the halo taps.
//
// Block = (n, 2 output rows): 2048 blocks, 512 threads.
//   phase 1 (-> barrier 1): threads 0..255 pack 4 halo rows into LDS tiles
//     (1 uint4-quad each, bit = signbit); threads 256..511 compute the 288
//     packed weight words pws[o*9+t] (bit c = w<0) from wt (36 KB, L2-hot).
//   phase 2 (-> barrier 2): weight threads expand pws -> afsh MFMA A-frags
//     (o = lane&31, ch = (lane>>5)*16 + e) and compute csh BN tables.
//   conv: 8 waves, wave = (row = wave>>2, 64-px segment = wave&3), tap-outer
//     dual-accumulator loop; per tap: 1 LDS a-frag b128 read + 2 word reads,
//     bit-spread (x*0x204081) to {0,1} i8, 2 MFMAs. Epilogue: i32->f32,
//     fma with BN tables, ReLU, nontemporal coalesced stores.
// ---------------------------------------------------------------------------
__global__ __launch_bounds__(512) void biconv_mfma(
    const uint32_t* __restrict__ x, const float* __restrict__ wt,
    const float* __restrict__ gamma, const float* __restrict__ beta,
    const float* __restrict__ rmean, const float* __restrict__ rvar,
    float* __restrict__ out) {
    const uint32_t bid = blockIdx.x;                       // 0..2047
    const uint32_t wg  = ((bid & 7u) << 8) | (bid >> 3);   // bijective XCD chunk
    const int n   = wg >> 7;                               // 0..15
    const int h0  = (wg & 127) << 1;                       // 0,2,...,254
    const int tid  = threadIdx.x;
    const int lane = tid & 63;
    const int wave = tid >> 6;

    __shared__ uint32_t tiles[4][TWD];
    __shared__ uint4    afsh[9 * 64];     // 9216 B
    __shared__ float    csh[320];         // c0[0..287], c1[288..319]
    __shared__ uint32_t pws[COUT * 9];    // packed weights

    // ---- phase 1 ----
    if (tid < 256) {
        // pack 4 staged rows: r = tid>>6, quad q = tid&63
        const int r  = tid >> 6;
        const int q  = tid & 63;
        const int hr = h0 - 1 + r;                // -1 .. 256
        uint32_t b0 = 0, b1 = 0, b2 = 0, b3 = 0;
        if (hr >= 0 && hr < HH) {
            const uint32_t* xp = x + (size_t)n * (CIN * HWSZ) + (size_t)hr * WW + (q << 2);
#pragma unroll
            for (int c = 0; c < CIN; ++c) {
                const uint4 v = *reinterpret_cast<const uint4*>(xp + (size_t)c * HWSZ);
                b0 |= (v.x >> 31) << c;           // bit = signbit (x < 0)
                b1 |= (v.y >> 31) << c;
                b2 |= (v.z >> 31) << c;
                b3 |= (v.w >> 31) << c;
            }
        }
        *reinterpret_cast<uint4*>(&tiles[r][(q << 2) + 4]) = make_uint4(b0, b1, b2, b3);
    } else {
        const int t2 = tid - 256;                 // 0..255
        // packed weight words: j = t2 (0..255) and j = 256+t2 for t2<32
        {
            const int j = t2;
            const int o = j / 9, t = j % 9;
            uint32_t bits = 0;
#pragma unroll
            for (int c = 0; c < CIN; ++c)
                bits |= (wt[(o * CIN + c) * 9 + t] < 0.f) ? (1u << c) : 0u;
            pws[j] = bits;
        }
        if (t2 < 32) {
            const int j = 256 + t2;
            const int o = j / 9, t = j % 9;
            uint32_t bits = 0;
#pragma unroll
            for (int c = 0; c < CIN; ++c)
                bits |= (wt[(o * CIN + c) * 9 + t] < 0.f) ? (1u << c) : 0u;
            pws[j] = bits;
        }
        if (t2 < 8) tiles[t2 >> 1][(t2 & 1) ? 260 : 3] = 0u;   // zero column pads
    }
    __syncthreads();   // pws + tiles ready

    // ---- phase 2: A-fragments + BN tables (weight threads only) ----
    if (tid >= 256) {
        const int t2 = tid - 256;
        if (t2 < 64) {
            const int sh = (t2 & 32) >> 1;        // channel half 0/16
#pragma unroll
            for (int t = 0; t < 9; ++t) {
                const uint32_t chunk = pws[(t2 & 31) * 9 + t] >> sh;
                uint32_t w[4];
#pragma unroll
                for (int k = 0; k < 4; ++k) {
                    const uint32_t y = (((chunk >> (4 * k)) & 0xFu) * 0x204081u) & 0x01010101u;
                    w[k] = (y * 0xFEu) | 0x01010101u;   // bit? 0xFF(-1) : 0x01(+1)
                }
                afsh[t * 64 + t2] = make_uint4(w[0], w[1], w[2], w[3]);
            }
        }
#pragma unroll
        for (int it = 0; it < 2; ++it) {
            const int j = t2 + it * 256;
            if (j < 288) {
                const int cls = j >> 5;            // 0..8
                const int o   = j & 31;
                const int rc = cls / 3, cc = cls % 3;
                int wsum = 0;
#pragma unroll
                for (int dh = 0; dh < 3; ++dh)
#pragma unroll
                    for (int dw = 0; dw < 3; ++dw) {
                        const bool bad = (rc == 0 && dh == 0) || (rc == 2 && dh == 2) ||
                                         (cc == 0 && dw == 0) || (cc == 2 && dw == 2);
                        if (!bad) wsum += 32 - 2 * __popc(pws[o * 9 + dh * 3 + dw]);
                    }
                const float inv = gamma[o] * rsqrtf(rvar[o] + EPSV);
                csh[cls * 32 + o] = beta[o] - rmean[o] * inv + (float)wsum * inv;
                if (cls == 0) csh[288 + o] = -2.0f * inv;
            }
        }
    }
    __syncthreads();   // afsh + csh ready

    // ---- conv: wave = (row rsel, 64-px segment); 2 accumulator tiles ----
    const int l31  = lane & 31;
    const int shv  = (lane & 32) >> 1;     // channel half for B expansion
    const int og   = (lane >> 5) << 2;     // C/D row offset 0/4
    const int rsel = wave >> 2;            // output row within pair: 0/1
    const int pA   = ((wave & 3) << 6) + l31;   // tile A pixel
    const int pB   = pA + 32;                   // tile B pixel

    const int h  = h0 + rsel;
    const int rc = (h == 0) ? 0 : ((h == HH - 1) ? 2 : 1);

    v16i acc0 = {0}, acc1 = {0};
#pragma unroll
    for (int dh = 0; dh < 3; ++dh) {
        const uint32_t* trow = &tiles[rsel + dh][0];
#pragma unroll
        for (int dw = 0; dw < 3; ++dw) {
            const v4i a = *reinterpret_cast<const v4i*>(&afsh[(dh * 3 + dw) * 64 + lane]);
            const uint32_t hA = trow[pA + 3 + dw] >> shv;
            const uint32_t hB = trow[pB + 3 + dw] >> shv;
            v4i b;
            b.x = (int)((( hA        & 0xFu) * 0x204081u) & 0x01010101u);
            b.y = (int)((((hA >> 4)  & 0xFu) * 0x204081u) & 0x01010101u);
            b.z = (int)((((hA >> 8)  & 0xFu) * 0x204081u) & 0x01010101u);
            b.w = (int)((((hA >> 12) & 0xFu) * 0x204081u) & 0x01010101u);
            acc0 = __builtin_amdgcn_mfma_i32_32x32x32_i8(a, b, acc0, 0, 0, 0);
            b.x = (int)((( hB        & 0xFu) * 0x204081u) & 0x01010101u);
            b.y = (int)((((hB >> 4)  & 0xFu) * 0x204081u) & 0x01010101u);
            b.z = (int)((((hB >> 8)  & 0xFu) * 0x204081u) & 0x01010101u);
            b.w = (int)((((hB >> 12) & 0xFu) * 0x204081u) & 0x01010101u);
            acc1 = __builtin_amdgcn_mfma_i32_32x32x32_i8(a, b, acc1, 0, 0, 0);
        }
    }

    // ---- epilogue: C/D row = (e&3)+8*(e>>2)+og, col = pixel ----
    const int ccA = (pA == 0) ? 0 : ((pA == WW - 1) ? 2 : 1);
    const int ccB = (pB == WW - 1) ? 2 : 1;       // pB >= 32, never 0
    const float* c0A = &csh[(rc * 3 + ccA) * 32];
    const float* c0B = &csh[(rc * 3 + ccB) * 32];
    const float* c1  = &csh[288];
    float* outn = out + (size_t)n * (COUT * HWSZ) + (size_t)h * WW;
#pragma unroll
    for (int e = 0; e < 16; ++e) {
        const int o = (e & 3) + ((e >> 2) << 3) + og;
        const float vA = fmaf((float)acc0[e], c1[o], c0A[o]);
        const float vB = fmaf((float)acc1[e], c1[o], c0B[o]);
        __builtin_nontemporal_store(vA > 0.f ? vA : 0.f, outn + (size_t)o * HWSZ + pA);
        __builtin_nontemporal_store(vB > 0.f ? vB : 0.f, outn + (size_t)o * HWSZ + pB);
    }
}

// ---------------------------------------------------------------------------
extern "C" void kernel_launch(void* const* d_in, const int* in_sizes, int n_in,
                              void* d_out, int out_size, void* d_ws, size_t ws_size,
                              hipStream_t stream) {
    const float* x     = (const float*)d_in[0];
    const float* wt    = (const float*)d_in[1];
    const float* gamma = (const float*)d_in[2];
    const float* beta  = (const float*)d_in[3];
    const float* rmean = (const float*)d_in[4];
    const float* rvar  = (const float*)d_in[5];
    float* out = (float*)d_out;

    biconv_mfma<<<dim3(NB * HH / 2), dim3(512), 0, stream>>>(
        (const uint32_t*)x, wt, gamma, beta, rmean, rvar, out);
}

// Round 12
// 47.029 us; speedup vs baseline: 1.2060x; 1.0162x over previous
//
#include <hip/hip_runtime.h>
#include <stdint.h>

#define NB   16
#define CIN  32
#define COUT 32
#define HH   256
#define WW   256
#define HWSZ (HH * WW)
#define EPSV 1e-5f
#define TWD  264     // LDS row words: zero pads at index 3 and 260, data at 4..259

typedef int v4i  __attribute__((ext_vector_type(4)));
typedef int v16i __attribute__((ext_vector_type(16)));

// ---------------------------------------------------------------------------
// Single fused kernel: binarize + implicit-GEMM i8-MFMA conv + BN + ReLU,
// with per-block weight prep (no producer kernel, single launch).
//
// Math: wb = sign(sign(w)+0.01) = -1 iff w<0, +1 otherwise. B-matrix bit =
// signbit(x) (1 iff x<0), pads/invalid taps = 0, A holds wb as i8 +-1:
//   acc = sum_{x<0} wb  ->  conv = Wsum_valid - 2*acc
//   result = acc*c1 + c0,  c1 = -2*inv,  c0 = beta - mean*inv + Wsum*inv,
//   inv = gamma/sqrt(var+eps).   Boundary classes (9) fold the halo taps.
//
// Block = (n, 2 output rows): 2048 blocks, 512 threads.
//   phase 1 (-> barrier 1): threads 0..255 pack 4 halo rows into LDS tiles
//     (1 uint4-quad each, bit = signbit) with EXPLICIT 8-deep load batching
//     (v[8] keeps 8 independent uint4 loads in flight; launch_bounds(512,8)
//     allows 64 VGPR at unchanged 8-waves/SIMD occupancy);
//     threads 256..511 compute the 288 packed weight words pws (wt L2-hot).
//   phase 2 (-> barrier 2): weight threads expand pws -> afsh MFMA A-frags
//     (o = lane&31, ch = (lane>>5)*16 + e) and compute csh BN tables.
//   conv: 8 waves, wave = (row = wave>>2, 64-px segment = wave&3), tap-outer
//     dual-accumulator loop; per tap: 1 LDS a-frag b128 read + 2 word reads,
//     bit-spread (x*0x204081) to {0,1} i8, 2 MFMAs. Epilogue: i32->f32,
//     fma with BN tables, ReLU, nontemporal coalesced stores.
// ---------------------------------------------------------------------------
__global__ __launch_bounds__(512, 8) void biconv_mfma(
    const uint32_t* __restrict__ x, const float* __restrict__ wt,
    const float* __restrict__ gamma, const float* __restrict__ beta,
    const float* __restrict__ rmean, const float* __restrict__ rvar,
    float* __restrict__ out) {
    const uint32_t bid = blockIdx.x;                       // 0..2047
    const uint32_t wg  = ((bid & 7u) << 8) | (bid >> 3);   // bijective XCD chunk
    const int n   = wg >> 7;                               // 0..15
    const int h0  = (wg & 127) << 1;                       // 0,2,...,254
    const int tid  = threadIdx.x;
    const int lane = tid & 63;
    const int wave = tid >> 6;

    __shared__ uint32_t tiles[4][TWD];
    __shared__ uint4    afsh[9 * 64];     // 9216 B
    __shared__ float    csh[320];         // c0[0..287], c1[288..319]
    __shared__ uint32_t pws[COUT * 9];    // packed weights

    // ---- phase 1 ----
    if (tid < 256) {
        // pack 4 staged rows: r = tid>>6, quad q = tid&63
        const int r  = tid >> 6;
        const int q  = tid & 63;
        const int hr = h0 - 1 + r;                // -1 .. 256
        uint32_t b0 = 0, b1 = 0, b2 = 0, b3 = 0;
        if (hr >= 0 && hr < HH) {
            const uint32_t* xp = x + (size_t)n * (CIN * HWSZ) + (size_t)hr * WW + (q << 2);
#pragma unroll
            for (int g = 0; g < 4; ++g) {
                uint4 v[8];
#pragma unroll
                for (int k = 0; k < 8; ++k)
                    v[k] = *reinterpret_cast<const uint4*>(xp + (size_t)(g * 8 + k) * HWSZ);
#pragma unroll
                for (int k = 0; k < 8; ++k) {
                    const int c = g * 8 + k;
                    b0 |= (v[k].x >> 31) << c;    // bit = signbit (x < 0)
                    b1 |= (v[k].y >> 31) << c;
                    b2 |= (v[k].z >> 31) << c;
                    b3 |= (v[k].w >> 31) << c;
                }
            }
        }
        *reinterpret_cast<uint4*>(&tiles[r][(q << 2) + 4]) = make_uint4(b0, b1, b2, b3);
    } else {
        const int t2 = tid - 256;                 // 0..255
        // packed weight words: j = t2 (0..255) and j = 256+t2 for t2<32
        {
            const int j = t2;
            const int o = j / 9, t = j % 9;
            uint32_t bits = 0;
#pragma unroll
            for (int c = 0; c < CIN; ++c)
                bits |= (wt[(o * CIN + c) * 9 + t] < 0.f) ? (1u << c) : 0u;
            pws[j] = bits;
        }
        if (t2 < 32) {
            const int j = 256 + t2;
            const int o = j / 9, t = j % 9;
            uint32_t bits = 0;
#pragma unroll
            for (int c = 0; c < CIN; ++c)
                bits |= (wt[(o * CIN + c) * 9 + t] < 0.f) ? (1u << c) : 0u;
            pws[j] = bits;
        }
        if (t2 < 8) tiles[t2 >> 1][(t2 & 1) ? 260 : 3] = 0u;   // zero column pads
    }
    __syncthreads();   // pws + tiles ready

    // ---- phase 2: A-fragments + BN tables (weight threads only) ----
    if (tid >= 256) {
        const int t2 = tid - 256;
        if (t2 < 64) {
            const int sh = (t2 & 32) >> 1;        // channel half 0/16
#pragma unroll
            for (int t = 0; t < 9; ++t) {
                const uint32_t chunk = pws[(t2 & 31) * 9 + t] >> sh;
                uint32_t w[4];
#pragma unroll
                for (int k = 0; k < 4; ++k) {
                    const uint32_t y = (((chunk >> (4 * k)) & 0xFu) * 0x204081u) & 0x01010101u;
                    w[k] = (y * 0xFEu) | 0x01010101u;   // bit? 0xFF(-1) : 0x01(+1)
                }
                afsh[t * 64 + t2] = make_uint4(w[0], w[1], w[2], w[3]);
            }
        }
#pragma unroll
        for (int it = 0; it < 2; ++it) {
            const int j = t2 + it * 256;
            if (j < 288) {
                const int cls = j >> 5;            // 0..8
                const int o   = j & 31;
                const int rc = cls / 3, cc = cls % 3;
                int wsum = 0;
#pragma unroll
                for (int dh = 0; dh < 3; ++dh)
#pragma unroll
                    for (int dw = 0; dw < 3; ++dw) {
                        const bool bad = (rc == 0 && dh == 0) || (rc == 2 && dh == 2) ||
                                         (cc == 0 && dw == 0) || (cc == 2 && dw == 2);
                        if (!bad) wsum += 32 - 2 * __popc(pws[o * 9 + dh * 3 + dw]);
                    }
                const float inv = gamma[o] * rsqrtf(rvar[o] + EPSV);
                csh[cls * 32 + o] = beta[o] - rmean[o] * inv + (float)wsum * inv;
                if (cls == 0) csh[288 + o] = -2.0f * inv;
            }
        }
    }
    __syncthreads();   // afsh + csh ready

    // ---- conv: wave = (row rsel, 64-px segment); 2 accumulator tiles ----
    const int l31  = lane & 31;
    const int shv  = (lane & 32) >> 1;     // channel half for B expansion
    const int og   = (lane >> 5) << 2;     // C/D row offset 0/4
    const int rsel = wave >> 2;            // output row within pair: 0/1
    const int pA   = ((wave & 3) << 6) + l31;   // tile A pixel
    const int pB   = pA + 32;                   // tile B pixel

    const int h  = h0 + rsel;
    const int rc = (h == 0) ? 0 : ((h == HH - 1) ? 2 : 1);

    v16i acc0 = {0}, acc1 = {0};
#pragma unroll
    for (int dh = 0; dh < 3; ++dh) {
        const uint32_t* trow = &tiles[rsel + dh][0];
#pragma unroll
        for (int dw = 0; dw < 3; ++dw) {
            const v4i a = *reinterpret_cast<const v4i*>(&afsh[(dh * 3 + dw) * 64 + lane]);
            const uint32_t hA = trow[pA + 3 + dw] >> shv;
            const uint32_t hB = trow[pB + 3 + dw] >> shv;
            v4i b;
            b.x = (int)((( hA        & 0xFu) * 0x204081u) & 0x01010101u);
            b.y = (int)((((hA >> 4)  & 0xFu) * 0x204081u) & 0x01010101u);
            b.z = (int)((((hA >> 8)  & 0xFu) * 0x204081u) & 0x01010101u);
            b.w = (int)((((hA >> 12) & 0xFu) * 0x204081u) & 0x01010101u);
            acc0 = __builtin_amdgcn_mfma_i32_32x32x32_i8(a, b, acc0, 0, 0, 0);
            b.x = (int)((( hB        & 0xFu) * 0x204081u) & 0x01010101u);
            b.y = (int)((((hB >> 4)  & 0xFu) * 0x204081u) & 0x01010101u);
            b.z = (int)((((hB >> 8)  & 0xFu) * 0x204081u) & 0x01010101u);
            b.w = (int)((((hB >> 12) & 0xFu) * 0x204081u) & 0x01010101u);
            acc1 = __builtin_amdgcn_mfma_i32_32x32x32_i8(a, b, acc1, 0, 0, 0);
        }
    }

    // ---- epilogue: C/D row = (e&3)+8*(e>>2)+og, col = pixel ----
    const int ccA = (pA == 0) ? 0 : ((pA == WW - 1) ? 2 : 1);
    const int ccB = (pB == WW - 1) ? 2 : 1;       // pB >= 32, never 0
    const float* c0A = &csh[(rc * 3 + ccA) * 32];
    const float* c0B = &csh[(rc * 3 + ccB) * 32];
    const float* c1  = &csh[288];
    float* outn = out + (size_t)n * (COUT * HWSZ) + (size_t)h * WW;
#pragma unroll
    for (int e = 0; e < 16; ++e) {
        const int o = (e & 3) + ((e >> 2) << 3) + og;
        const float vA = fmaf((float)acc0[e], c1[o], c0A[o]);
        const float vB = fmaf((float)acc1[e], c1[o], c0B[o]);
        __builtin_nontemporal_store(vA > 0.f ? vA : 0.f, outn + (size_t)o * HWSZ + pA);
        __builtin_nontemporal_store(vB > 0.f ? vB : 0.f, outn + (size_t)o * HWSZ + pB);
    }
}

// ---------------------------------------------------------------------------
extern "C" void kernel_launch(void* const* d_in, const int* in_sizes, int n_in,
                              void* d_out, int out_size, void* d_ws, size_t ws_size,
                              hipStream_t stream) {
    const float* x     = (const float*)d_in[0];
    const float* wt    = (const float*)d_in[1];
    const float* gamma = (const float*)d_in[2];
    const float* beta  = (const float*)d_in[3];
    const float* rmean = (const float*)d_in[4];
    const float* rvar  = (const float*)d_in[5];
    float* out = (float*)d_out;

    biconv_mfma<<<dim3(NB * HH / 2), dim3(512), 0, stream>>>(
        (const uint32_t*)x, wt, gamma, beta, rmean, rvar, out);
}